// Round 6
// baseline (302.309 us; speedup 1.0000x reference)
//
#include <hip/hip_runtime.h>

// NCC loss: 1 - mean( cross^2 / (pvar*tvar + 1e-8) ) over 9^3 zero-padded
// box windows, input (4,1,160,160,160) fp32.
//
// R11: R10 post-mortem — regression came from deleting prefetch-ahead (loads
// consumed ~20 insts after issue = full latency exposure) + mild spill.
// Reverted to R9 structure (125us best: depth-1 prefetch, dedicated
// reduction wave, one barrier/step). New change: the 72-float rp/rt register
// RING is deleted. VGPR_Count=76 hides the ring's ~92 AGPRs (unified file)
// -> ~168 regs/wave -> only 3 waves/SIMD; occupancy (not barriers) is the
// cap for this latency-bound kernel. The subtract slice (z-9) was read by
// this block 9 steps ago and is L2/L3-resident (~40KB/block history), so we
// RE-LOAD it per step (2 float4 L2 hits). Bit-identical arithmetic; gate
// zS >= max(z0-4,0) reproduces the ring's zero-initialized slots at chunk
// start. Ring gone -> ~80-90 regs -> 5-6 waves/SIMD (20-24 waves/CU), grid
// near-fully resident. launch_bounds(256,5) keeps the allocator at <=102
// regs (no spill: WRITE_SIZE must stay ~50KB). Slot-unroll machinery gone
// (plain loop, static buffer parity via 2 steps/iter).

#define DSZ    160
#define NBATCH 4
#define RAD    4
#define TX     16
#define TY     16
#define ZCHUNK 40
#define SLICE  (DSZ*DSZ)
#define VOL    (DSZ*DSZ*DSZ)
#define WINV   (1.0f/729.0f)
#define NVOX_INV (1.0f/16384000.0f)

#define NROW 24        // halo rows per tile
#define NGRP 6         // x groups of 4 halo cols (24)
#define BLK  256       // 3 staging waves (tid<192) + 1 reduction wave

#define S2_RS 20                 // row stride: 16 outputs + pad (2-way banks)
#define S2_FS (NROW*S2_RS)       // 480 floats per field
#define S2_BUF (5*S2_FS)         // 2400 floats per parity buffer

__device__ __forceinline__ float dpp_shl1(float x) {  // lane i <- lane i+1 (16-lane row, OOB=0)
    return __int_as_float(__builtin_amdgcn_update_dpp(0, __float_as_int(x), 0x101, 0xf, 0xf, true));
}
__device__ __forceinline__ float dpp_shl2(float x) {  // lane i <- lane i+2
    return __int_as_float(__builtin_amdgcn_update_dpp(0, __float_as_int(x), 0x102, 0xf, 0xf, true));
}

__global__ __launch_bounds__(BLK, 5)
void ncc_main(const float* __restrict__ pred, const float* __restrict__ tgt,
              float* __restrict__ accum)
{
    const int tid = threadIdx.x;
    const int row = tid >> 3;      // 0..23 halo row (staging threads)
    const int g   = tid & 7;       // 0..7; g<6 = active x-group
    const int ox  = blockIdx.x * TX;
    const int oy  = blockIdx.y * TY;
    const int batch = blockIdx.z >> 2;
    const int z0  = (blockIdx.z & 3) * ZCHUNK;

    __shared__ float s2[2*S2_BUF];   // 19.2 KB, double-buffered [f][y][x pad20]

    const bool stg = (tid < 192) && (g < NGRP);
    const bool red = (tid >= 192);               // dedicated reduction wave
    const int  gy  = oy - RAD + row;
    const int  gx0 = ox - RAD + g*4;
    const bool ldok = stg && (gy >= 0) && (gy < DSZ) && (gx0 >= 0) && (gx0 + 3 < DSZ);
    const int  base = batch*VOL + gy*DSZ + gx0;     // only used under ldok

    // running z-window sums (5 fields x own 4 columns)
    float zs[5][4];
    #pragma unroll
    for (int f = 0; f < 5; ++f)
        #pragma unroll
        for (int j = 0; j < 4; ++j) zs[f][j] = 0.f;

    // lowest z ever accumulated (for the subtract gate)
    const int zlo = (z0 - RAD < 0) ? 0 : (z0 - RAD);

    // ---- warm-up: slices z0-4 .. z0+3 into zs (no ring) ----
    if (stg) {
        #pragma unroll
        for (int i = 0; i < 8; ++i) {
            int z = z0 - RAD + i;
            if (z >= 0) {                       // uniform; z < DSZ always here
                float4 p4 = {0,0,0,0}, t4 = {0,0,0,0};
                if (ldok) {
                    p4 = *(const float4*)(pred + base + z*SLICE);
                    t4 = *(const float4*)(tgt  + base + z*SLICE);
                }
                const float pc[4] = {p4.x,p4.y,p4.z,p4.w};
                const float tc[4] = {t4.x,t4.y,t4.z,t4.w};
                #pragma unroll
                for (int j = 0; j < 4; ++j) {
                    zs[0][j] += pc[j];        zs[1][j] += tc[j];
                    zs[2][j] += pc[j]*pc[j];  zs[3][j] += tc[j]*tc[j];
                    zs[4][j] += pc[j]*tc[j];
                }
            }
        }
    }

    // ---- streaming prefetch of the next add-slice (depth 1) ----
    int za = z0 + RAD;                      // absolute z of next fetch
    int zmax = z0 + ZCHUNK + RAD;           // last useful slice + 1
    if (zmax > DSZ) zmax = DSZ;
    float4 pa4 = {0,0,0,0}, ta4 = {0,0,0,0};

#define PF_NEXT() do {                                                        \
    float4 _p = {0,0,0,0}, _t = {0,0,0,0};                                    \
    if (ldok && za < zmax) {                                                  \
        _p = *(const float4*)(pred + base + za*SLICE);                        \
        _t = *(const float4*)(tgt  + base + za*SLICE);                        \
    }                                                                         \
    pa4 = _p; ta4 = _t; ++za;                                                 \
} while (0)

    if (stg) PF_NEXT();  // slice for step 0

    float acc = 0.f;

#define NCC_STEP(BUFI) do {                                                   \
    float* s2w = s2 + (BUFI)*S2_BUF;                                          \
    if (stg) {                                                                \
        /* subtract slice z-9: re-read from L2/L3 (this block fetched it */   \
        /* 9 steps ago). Gate: only slices actually accumulated. */           \
        const int zS = za - 10;                                               \
        float4 ps4 = {0,0,0,0}, ts4 = {0,0,0,0};                              \
        if (ldok && zS >= zlo) {                                              \
            ps4 = *(const float4*)(pred + base + zS*SLICE);                   \
            ts4 = *(const float4*)(tgt  + base + zS*SLICE);                   \
        }                                                                     \
        const float pc[4] = {pa4.x,pa4.y,pa4.z,pa4.w};                        \
        const float tc[4] = {ta4.x,ta4.y,ta4.z,ta4.w};                        \
        PF_NEXT();  /* issue slice s+1; full step to complete */              \
        const float psv[4] = {ps4.x,ps4.y,ps4.z,ps4.w};                       \
        const float tsv[4] = {ts4.x,ts4.y,ts4.z,ts4.w};                       \
        _Pragma("unroll")                                                     \
        for (int j = 0; j < 4; ++j) {                                         \
            float ps = psv[j], qs = tsv[j];                                   \
            float d0 = pc[j] - ps, d1 = tc[j] - qs;                           \
            zs[0][j] += d0;                                                   \
            zs[1][j] += d1;                                                   \
            zs[2][j] += d0*(pc[j] + ps);                                      \
            zs[3][j] += d1*(tc[j] + qs);                                      \
            zs[4][j] += pc[j]*tc[j] - ps*qs;                                  \
        }                                                                     \
        _Pragma("unroll")                                                     \
        for (int f = 0; f < 5; ++f) {                                         \
            float P0 = zs[f][0];                                              \
            float P1 = P0 + zs[f][1];                                         \
            float P2 = P1 + zs[f][2];                                         \
            float P3 = P2 + zs[f][3];                                         \
            float T  = dpp_shl1(P3);                                          \
            float Q0 = dpp_shl2(P0), Q1 = dpp_shl2(P1);                       \
            float Q2 = dpp_shl2(P2), Q3 = dpp_shl2(P3);                       \
            if (g < 4) {                                                      \
                float b = P3 + T;                                             \
                float* dst = &s2w[f*S2_FS + row*S2_RS + g*4];                 \
                dst[0] = b + Q0;                                              \
                dst[1] = b - P0 + Q1;                                         \
                dst[2] = b - P1 + Q2;                                         \
                dst[3] = b - P2 + Q3;                                         \
            }                                                                 \
        }                                                                     \
    }                                                                         \
    __syncthreads();                                                          \
    if (red) {                                                                \
        const int x = tid & 15, yq = ((tid >> 4) & 3)*4;                      \
        float S[5][4];                                                        \
        _Pragma("unroll")                                                     \
        for (int f = 0; f < 5; ++f) {                                         \
            const float* col = &s2w[f*S2_FS + x];                             \
            float r0 = col[(yq+0)*S2_RS], r1 = col[(yq+1)*S2_RS];             \
            float r2 = col[(yq+2)*S2_RS], r3 = col[(yq+3)*S2_RS];             \
            float run = r0+r1+r2+r3 + col[(yq+4)*S2_RS] + col[(yq+5)*S2_RS]   \
                      + col[(yq+6)*S2_RS] + col[(yq+7)*S2_RS];                \
            run += col[(yq+8)*S2_RS];        S[f][0] = run;                   \
            run += col[(yq+9)*S2_RS]  - r0;  S[f][1] = run;                   \
            run += col[(yq+10)*S2_RS] - r1;  S[f][2] = run;                   \
            run += col[(yq+11)*S2_RS] - r2;  S[f][3] = run;                   \
        }                                                                     \
        _Pragma("unroll")                                                     \
        for (int i = 0; i < 4; ++i) {                                         \
            float Sp = S[0][i], St = S[1][i];                                 \
            float cross = S[4][i] - Sp*St*WINV;                               \
            float pv    = S[2][i] - Sp*Sp*WINV;                               \
            float tv    = S[3][i] - St*St*WINV;                               \
            acc += cross*cross / (pv*tv + 1e-8f);                             \
        }                                                                     \
    }                                                                         \
} while (0)

    // 40 steps, static buffer parity (2 steps per iteration)
    for (int it = 0; it < ZCHUNK/2; ++it) {
        NCC_STEP(0);
        NCC_STEP(1);
    }
#undef NCC_STEP
#undef PF_NEXT

    // all cc partials live in the reduction wave (tid 192..255)
    if (red) {
        float v = acc;
        #pragma unroll
        for (int off = 32; off > 0; off >>= 1) v += __shfl_down(v, off, 64);
        if (tid == 192) atomicAdd(accum, v);
    }
}

__global__ void ncc_final(const float* __restrict__ accum, float* __restrict__ out)
{
    out[0] = 1.0f - accum[0] * NVOX_INV;
}

extern "C" void kernel_launch(void* const* d_in, const int* in_sizes, int n_in,
                              void* d_out, int out_size, void* d_ws, size_t ws_size,
                              hipStream_t stream)
{
    const float* pred = (const float*)d_in[0];
    const float* tgt  = (const float*)d_in[1];
    float* out = (float*)d_out;
    float* ws  = (float*)d_ws;

    hipMemsetAsync(ws, 0, sizeof(float), stream);
    dim3 grid(DSZ/TX, DSZ/TY, NBATCH*4);   // 10 x 10 x 16 = 1600 blocks
    ncc_main<<<grid, BLK, 0, stream>>>(pred, tgt, ws);
    ncc_final<<<1, 1, 0, stream>>>(ws, out);
}